// Round 19
// baseline (2440.974 us; speedup 1.0000x reference)
//
#include <hip/hip_runtime.h>
#include <hip/hip_bf16.h>

typedef __hip_bfloat16 hbf16;
typedef __attribute__((ext_vector_type(8))) short bfrag8;
typedef __attribute__((ext_vector_type(4))) short short4v;
typedef __attribute__((ext_vector_type(4))) float f32x4;

#define BATCH 16
#define HH 512
#define WW 512
#define HWSZ (HH * WW)
#define STRIPH 64
#define NSTEP (STRIPH / 4)

__device__ __forceinline__ short f2bf(float f) {
    hbf16 h = __float2bfloat16(f);
    return *(short*)&h;
}

// circular slot in a 6-row window (r >= -5 always; +600 keeps it positive)
__device__ __forceinline__ int slot6(int r) { return (r + 600) % 6; }

__device__ __forceinline__ float blockSum(float v) {
#pragma unroll
    for (int o = 32; o > 0; o >>= 1) v += __shfl_down(v, o, 64);
    __shared__ float sh[4];
    const int lane = threadIdx.x & 63, wid = threadIdx.x >> 6;
    if (lane == 0) sh[wid] = v;
    __syncthreads();
    float r = 0.f;
    if (threadIdx.x == 0) r = sh[0] + sh[1] + sh[2] + sh[3];
    __syncthreads();
    return r;
}

// Generic conv16 row into a 6-slot LDS window. Captures: lx, cib, c0, tx0,
// dys, dxs. AF must be a named bfrag8[5] (stays in regs).
#define CONV_ROW(INW, IW, OUTW, OW, AF, B0_, B1_, B2_, B3_, GR) do {          \
    const int gr_ = (GR);                                                      \
    const bool rok_ = ((unsigned)gr_ < (unsigned)HH);                          \
    const int halo_ = ((OW) - 64) / 2;                                         \
    const int rslot_ = slot6(gr_) * (OW);                                      \
    const int rm1_ = slot6(gr_ - 1) * (IW);                                    \
    const int r00_ = slot6(gr_) * (IW);                                        \
    const int rp1_ = slot6(gr_ + 1) * (IW);                                    \
    _Pragma("unroll")                                                          \
    for (int c_ = 0; c_ < 5; ++c_) {                                           \
        const int xr_ = c_ * 16 + lx;                                          \
        const int xc_ = (xr_ < (OW)) ? xr_ : ((OW) - 1);                       \
        f32x4 a_ = { B0_, B1_, B2_, B3_ };                                     \
        _Pragma("unroll")                                                      \
        for (int s_ = 0; s_ < 5; ++s_) {                                       \
            const int rof_ = (dys[s_] == 0) ? rm1_ : ((dys[s_] == 2) ? rp1_ : r00_); \
            const bfrag8 q_ = *(const bfrag8*)&(INW)[(rof_ + (xc_ + dxs[s_])) * 16 + cib]; \
            a_ = __builtin_amdgcn_mfma_f32_16x16x32_bf16(AF[s_], q_, a_, 0, 0, 0); \
        }                                                                      \
        if (xr_ < (OW)) {                                                      \
            const int gx_ = tx0 - halo_ + xr_;                                 \
            const bool ok_ = rok_ && ((unsigned)gx_ < (unsigned)WW);           \
            short4v st_;                                                       \
            _Pragma("unroll")                                                  \
            for (int i_ = 0; i_ < 4; ++i_) {                                   \
                float r_ = a_[i_]; r_ = (r_ >= 0.f) ? r_ : 0.01f * r_;         \
                st_[i_] = ok_ ? f2bf(r_) : (short)0;                           \
            }                                                                  \
            *(short4v*)&(OUTW)[(rslot_ + xr_) * 16 + c0] = st_;                \
        }                                                                      \
    }                                                                          \
} while (0)

// ---------------------------------------------------------------------------
// quadA: L0(2ch fp32 -> 16) + L1 + L2 + L3, rolling 6-slot windows over a
// 64x64 strip. Windows: fin 72w(2ch), a0 70w, a1 68w, a2 66w = 40.9 KB ->
// 4 blocks/CU. Slot-lifetime: every overwrite >=1 barrier from last reader.
// ---------------------------------------------------------------------------
__global__ __launch_bounds__(256, 4) void k_quadA(
    const float* __restrict__ p0, long long s0,
    const float* __restrict__ p1, long long s1,
    short* __restrict__ outA,
    const float* __restrict__ w0, const float* __restrict__ b0,
    const float* __restrict__ w1, const float* __restrict__ b1,
    const float* __restrict__ w2, const float* __restrict__ b2,
    const float* __restrict__ w3, const float* __restrict__ b3)
{
    __shared__ short finW[6 * 72 * 2];     //  1,728 B
    __shared__ short a0W[6 * 70 * 16];     // 13,440 B
    __shared__ short a1W[6 * 68 * 16];     // 13,056 B
    __shared__ short a2W[6 * 66 * 16];     // 12,672 B

    const int tid = threadIdx.x, lane = tid & 63, wv = tid >> 6;
    const int tx0 = blockIdx.x * 64, Y0 = blockIdx.y * STRIPH;
    const long long b = blockIdx.z;
    const float* pa = p0 + b * s0;
    const float* pb = p1 + b * s1;
    short* outb = outA + b * (long long)HWSZ * 16;

    const int arow = lane & 15, grp = lane >> 4, lx = lane & 15;
    const int half = grp & 1, cib = half * 8, kofb = grp >> 1;
    const int c0 = grp * 4;

    bfrag8 a0f;
#pragma unroll
    for (int j = 0; j < 8; ++j) {
        const int k = grp * 8 + j;
        a0f[j] = (k < 18) ? f2bf(w0[arow * 18 + (k & 1) * 9 + (k >> 1)]) : (short)0;
    }
    bfrag8 af1[5], af2[5], af3[5];
    int dys[5], dxs[5];
#pragma unroll
    for (int s = 0; s < 5; ++s) {
        const int koff = 2 * s + kofb;
        const int kc = (koff < 9) ? koff : 8;
        dys[s] = kc / 3; dxs[s] = kc - dys[s] * 3;
#pragma unroll
        for (int j = 0; j < 8; ++j) {
            af1[s][j] = (koff < 9) ? f2bf(w1[(arow * 16 + cib + j) * 9 + koff]) : (short)0;
            af2[s][j] = (koff < 9) ? f2bf(w2[(arow * 16 + cib + j) * 9 + koff]) : (short)0;
            af3[s][j] = (koff < 9) ? f2bf(w3[(arow * 16 + cib + j) * 9 + koff]) : (short)0;
        }
    }
    const float b00 = b0[c0], b01 = b0[c0 + 1], b02 = b0[c0 + 2], b03 = b0[c0 + 3];
    const float b10 = b1[c0], b11 = b1[c0 + 1], b12 = b1[c0 + 2], b13 = b1[c0 + 3];
    const float b20 = b2[c0], b21 = b2[c0 + 1], b22 = b2[c0 + 2], b23 = b2[c0 + 3];
    const float b30 = b3[c0], b31 = b3[c0 + 1], b32 = b3[c0 + 2], b33 = b3[c0 + 3];

    auto STAGE = [&](int r0, int nr) {
        const int tot = nr * 144;   // 72 px x 2 ch
        for (int i = tid; i < tot; i += 256) {
            const int rr = i / 144, rem = i - rr * 144, xx = rem >> 1, ci = rem & 1;
            const int gr = r0 + rr, gx = tx0 - 4 + xx;
            float v = 0.f;
            if ((unsigned)gr < (unsigned)HH && (unsigned)gx < (unsigned)WW)
                v = (ci ? pb : pa)[gr * WW + gx];
            finW[(slot6(gr) * 72 + xx) * 2 + ci] = f2bf(v);
        }
    };

    auto L0ROW = [&](int gr) {   // a0 row gr, width 70, out base tx0-3
        const bool rok = ((unsigned)gr < (unsigned)HH);
        const int rslot = slot6(gr) * 70;
        const int rm1 = slot6(gr - 1) * 72, r00 = slot6(gr) * 72, rp1 = slot6(gr + 1) * 72;
#pragma unroll
        for (int c = 0; c < 5; ++c) {
            const int xr = c * 16 + lx;
            const int xc = (xr < 70) ? xr : 69;
            bfrag8 bf;
#pragma unroll
            for (int j = 0; j < 8; ++j) {
                const int k = grp * 8 + j;
                short v = 0;
                if (k < 18) {
                    const int tap = k >> 1, dy = tap / 3, dx = tap - dy * 3;
                    const int ro = (dy == 0) ? rm1 : ((dy == 2) ? rp1 : r00);
                    v = finW[(ro + (xc + dx)) * 2 + (k & 1)];
                }
                bf[j] = v;
            }
            f32x4 a = { b00, b01, b02, b03 };
            a = __builtin_amdgcn_mfma_f32_16x16x32_bf16(a0f, bf, a, 0, 0, 0);
            if (xr < 70) {
                const int gx = tx0 - 3 + xr;
                const bool ok = rok && ((unsigned)gx < (unsigned)WW);
                short4v st;
#pragma unroll
                for (int i = 0; i < 4; ++i) {
                    float r = a[i]; r = (r >= 0.f) ? r : 0.01f * r;
                    st[i] = ok ? f2bf(r) : (short)0;
                }
                *(short4v*)&a0W[(rslot + xr) * 16 + c0] = st;
            }
        }
    };

    auto OUT3 = [&](int gr) {    // rows/cols always in-image
        const int rm1 = slot6(gr - 1) * 66, r00 = slot6(gr) * 66, rp1 = slot6(gr + 1) * 66;
#pragma unroll
        for (int c = 0; c < 4; ++c) {
            const int o = c * 16 + lx;
            f32x4 a = { b30, b31, b32, b33 };
#pragma unroll
            for (int s = 0; s < 5; ++s) {
                const int rof = (dys[s] == 0) ? rm1 : ((dys[s] == 2) ? rp1 : r00);
                const bfrag8 q = *(const bfrag8*)&a2W[(rof + (o + dxs[s])) * 16 + cib];
                a = __builtin_amdgcn_mfma_f32_16x16x32_bf16(af3[s], q, a, 0, 0, 0);
            }
            short4v st;
#pragma unroll
            for (int i = 0; i < 4; ++i) {
                float r = a[i];
                st[i] = f2bf(r >= 0.f ? r : 0.01f * r);
            }
            *(short4v*)&outb[((long long)gr * WW + tx0 + o) * 16 + c0] = st;
        }
    };

    // prologue (6-slot constrained)
    STAGE(Y0 - 4, 6);                       // rows Y0-4..Y0+1
    __syncthreads();
    L0ROW(Y0 - 3 + wv);                     // a0 rows Y0-3..Y0
    __syncthreads();
    STAGE(Y0 + 2, 2);                       // rows Y0+2,Y0+3
    __syncthreads();
    if (wv < 2) L0ROW(Y0 + 1 + wv);         // a0 rows Y0+1,Y0+2
    __syncthreads();
    CONV_ROW(a0W, 70, a1W, 68, af1, b10, b11, b12, b13, Y0 - 2 + wv);
    __syncthreads();
    if (wv < 2) CONV_ROW(a1W, 68, a2W, 66, af2, b20, b21, b22, b23, Y0 - 1 + wv);
    __syncthreads();

    for (int k = 0; k < NSTEP; ++k) {
        const int base = Y0 + 4 * k;
        STAGE(base + 4, 4);
        __syncthreads();
        L0ROW(base + 3 + wv);
        __syncthreads();
        CONV_ROW(a0W, 70, a1W, 68, af1, b10, b11, b12, b13, base + 2 + wv);
        __syncthreads();
        CONV_ROW(a1W, 68, a2W, 66, af2, b20, b21, b22, b23, base + 1 + wv);
        __syncthreads();
        OUT3(base + wv);
    }
}

// ---------------------------------------------------------------------------
// quadB: L4 + L5 + L6 + L7(clip/median3/subtract), 6-slot rolling windows.
// Windows: in 72w, a4 70w, a5 68w, a6 66w (16ch) = 52.9 KB -> 3 blocks/CU.
// ---------------------------------------------------------------------------
__global__ __launch_bounds__(256, 4) void k_quadB(
    const short* __restrict__ inA,
    const float* __restrict__ xsrc, long long xstride,
    float* __restrict__ outp,
    const float* __restrict__ w4, const float* __restrict__ b4,
    const float* __restrict__ w5, const float* __restrict__ b5,
    const float* __restrict__ w6, const float* __restrict__ b6,
    const float* __restrict__ w7, const float* __restrict__ b7)
{
    __shared__ short inW[6 * 72 * 16];    // 13,824 B
    __shared__ short a4W[6 * 70 * 16];    // 13,440 B
    __shared__ short a5W[6 * 68 * 16];    // 13,056 B
    __shared__ short a6W[6 * 66 * 16];    // 12,672 B

    const int tid = threadIdx.x, lane = tid & 63, wv = tid >> 6;
    const int tx0 = blockIdx.x * 64, Y0 = blockIdx.y * STRIPH;
    const long long b = blockIdx.z;
    const short* inb = inA + b * (long long)HWSZ * 16;
    const float* xb = xsrc + b * xstride;
    float* ob = outp + b * (long long)HWSZ;

    const int arow = lane & 15, grp = lane >> 4, lx = lane & 15;
    const int half = grp & 1, cib = half * 8, kofb = grp >> 1;
    const int c0 = grp * 4;

    bfrag8 af4[5], af5[5], af6[5], lf[5];
    int dys[5], dxs[5];
#pragma unroll
    for (int s = 0; s < 5; ++s) {
        const int koff = 2 * s + kofb;
        const int kc = (koff < 9) ? koff : 8;
        dys[s] = kc / 3; dxs[s] = kc - dys[s] * 3;
#pragma unroll
        for (int j = 0; j < 8; ++j) {
            af4[s][j] = (koff < 9) ? f2bf(w4[(arow * 16 + cib + j) * 9 + koff]) : (short)0;
            af5[s][j] = (koff < 9) ? f2bf(w5[(arow * 16 + cib + j) * 9 + koff]) : (short)0;
            af6[s][j] = (koff < 9) ? f2bf(w6[(arow * 16 + cib + j) * 9 + koff]) : (short)0;
            lf[s][j]  = (arow < 3 && koff < 9) ? f2bf(w7[(arow * 16 + cib + j) * 9 + koff]) : (short)0;
        }
    }
    const float b40 = b4[c0], b41 = b4[c0 + 1], b42 = b4[c0 + 2], b43 = b4[c0 + 3];
    const float b50 = b5[c0], b51 = b5[c0 + 1], b52 = b5[c0 + 2], b53 = b5[c0 + 3];
    const float b60 = b6[c0], b61 = b6[c0 + 1], b62 = b6[c0 + 2], b63 = b6[c0 + 3];
    const float lb0 = (grp == 0) ? b7[0] : 0.f;
    const float lb1 = (grp == 0) ? b7[1] : 0.f;
    const float lb2 = (grp == 0) ? b7[2] : 0.f;

    auto STAGEB = [&](int r0, int nr) {
        const int tot = nr * 144;   // 72 granules x 2 halves
        for (int i = tid; i < tot; i += 256) {
            const int rr = i / 144, rem = i - rr * 144, ix = rem >> 1, hf = rem & 1;
            const int gr = r0 + rr, gx = tx0 - 4 + ix;
            bfrag8 v = {0, 0, 0, 0, 0, 0, 0, 0};
            if ((unsigned)gr < (unsigned)HH && (unsigned)gx < (unsigned)WW)
                v = *(const bfrag8*)&inb[((long long)gr * WW + gx) * 16 + hf * 8];
            *(bfrag8*)&inW[(slot6(gr) * 72 + ix) * 16 + hf * 8] = v;
        }
    };

    auto OUT7 = [&](int gr) {
        const int rm1 = slot6(gr - 1) * 66, r00 = slot6(gr) * 66, rp1 = slot6(gr + 1) * 66;
#pragma unroll
        for (int c = 0; c < 4; ++c) {
            const int o = c * 16 + lx;
            f32x4 a = { lb0, lb1, lb2, 0.f };
#pragma unroll
            for (int s = 0; s < 5; ++s) {
                const int rof = (dys[s] == 0) ? rm1 : ((dys[s] == 2) ? rp1 : r00);
                const bfrag8 q = *(const bfrag8*)&a6W[(rof + (o + dxs[s])) * 16 + cib];
                a = __builtin_amdgcn_mfma_f32_16x16x32_bf16(lf[s], q, a, 0, 0, 0);
            }
            if (grp == 0) {
                float y0 = fminf(fmaxf(a[0], -1.f), 1.f);
                float y1 = fminf(fmaxf(a[1], -1.f), 1.f);
                float y2 = fminf(fmaxf(a[2], -1.f), 1.f);
                float med = fmaxf(fminf(y0, fmaxf(y1, y2)), fminf(y1, y2));
                const long long pix = (long long)gr * WW + tx0 + o;
                ob[pix] = xb[pix] - med;
            }
        }
    };

    // prologue (6-slot constrained)
    STAGEB(Y0 - 4, 6);
    __syncthreads();
    CONV_ROW(inW, 72, a4W, 70, af4, b40, b41, b42, b43, Y0 - 3 + wv);
    __syncthreads();
    STAGEB(Y0 + 2, 2);
    __syncthreads();
    if (wv < 2) CONV_ROW(inW, 72, a4W, 70, af4, b40, b41, b42, b43, Y0 + 1 + wv);
    __syncthreads();
    CONV_ROW(a4W, 70, a5W, 68, af5, b50, b51, b52, b53, Y0 - 2 + wv);
    __syncthreads();
    if (wv < 2) CONV_ROW(a5W, 68, a6W, 66, af6, b60, b61, b62, b63, Y0 - 1 + wv);
    __syncthreads();

    for (int k = 0; k < NSTEP; ++k) {
        const int base = Y0 + 4 * k;
        STAGEB(base + 4, 4);
        __syncthreads();
        CONV_ROW(inW, 72, a4W, 70, af4, b40, b41, b42, b43, base + 3 + wv);
        __syncthreads();
        CONV_ROW(a4W, 70, a5W, 68, af5, b50, b51, b52, b53, base + 2 + wv);
        __syncthreads();
        CONV_ROW(a5W, 68, a6W, 66, af6, b60, b61, b62, b63, base + 1 + wv);
        __syncthreads();
        OUT7(base + wv);
    }
}

// ---------------------------------------------------------------------------
// Stats over x: float4 loads, per-wave LDS histograms, SSQ
// ---------------------------------------------------------------------------
__global__ __launch_bounds__(256) void k_stats_x(
    const float* __restrict__ x, unsigned* __restrict__ hist, float* __restrict__ sums)
{
    const int p = blockIdx.y;
    const f32x4* src = (const f32x4*)(x + (long long)p * HWSZ);
    __shared__ unsigned h[4][256];
    for (int i = threadIdx.x; i < 1024; i += 256) ((unsigned*)h)[i] = 0;
    __syncthreads();
    const int wid = threadIdx.x >> 6;

    float ss = 0.f;
    for (int i4 = blockIdx.x * 256 + threadIdx.x; i4 < HWSZ / 4; i4 += gridDim.x * 256) {
        const f32x4 v4 = src[i4];
#pragma unroll
        for (int e = 0; e < 4; ++e) {
            const float v = v4[e];
            ss += v * v;
            if (v >= -1.f && v <= 1.f) {
                int idx = (int)floorf((v + 1.f) * 128.f);
                idx = min(max(idx, 0), 255);
                atomicAdd(&h[wid][idx], 1u);
            }
        }
    }
    __syncthreads();
    const unsigned t = h[0][threadIdx.x] + h[1][threadIdx.x] +
                       h[2][threadIdx.x] + h[3][threadIdx.x];
    if (t) atomicAdd(&hist[p * 256 + threadIdx.x], t);

    float bs = blockSum(ss);
    if (threadIdx.x == 0) atomicAdd(&sums[0], bs);
}

// ---------------------------------------------------------------------------
// Stats over deltas, all 3 planes in one dispatch (z = channel).
// ---------------------------------------------------------------------------
__global__ __launch_bounds__(256) void k_stats_delta(
    const float* __restrict__ planes,
    unsigned* __restrict__ hist, float* __restrict__ sums)
{
    const int b = blockIdx.y, cz = blockIdx.z;
    const float* P = planes + ((long long)cz * BATCH + b) * HWSZ;
    const int row = b * 3 + cz;
    __shared__ unsigned h[4][256];
    for (int i = threadIdx.x; i < 1024; i += 256) ((unsigned*)h)[i] = 0;
    __syncthreads();
    const int wid = threadIdx.x >> 6;

    float ss = 0.f;
    for (int i4 = blockIdx.x * 256 + threadIdx.x; i4 < HWSZ / 4; i4 += gridDim.x * 256) {
        const int i0 = i4 * 4;
        const int y = i0 >> 9, x0 = i0 & (WW - 1);
        const f32x4 cur = ((const f32x4*)P)[i4];
        f32x4 up = { 0.f, 0.f, 0.f, 0.f };
        if (y) up = ((const f32x4*)P)[i4 - (WW / 4)];
        const float left = x0 ? P[i0 - 1] : 0.f;
        const float upl = (x0 && y) ? P[i0 - WW - 1] : 0.f;
#pragma unroll
        for (int e = 0; e < 4; ++e) {
            const float v = cur[e];
            const float n = up[e];
            const float wv = e ? cur[e - 1] : left;
            const float nw = e ? up[e - 1] : upl;
            float pr = n + wv - nw;
            pr = fminf(fmaxf(pr, fminf(n, wv)), fmaxf(n, wv));
            const float d = v - pr;
            ss += d * d;
            if (d >= -1.f && d <= 1.f) {
                int idx = (int)floorf((d + 1.f) * 128.f);
                idx = min(max(idx, 0), 255);
                atomicAdd(&h[wid][idx], 1u);
            }
        }
    }
    __syncthreads();
    const unsigned t = h[0][threadIdx.x] + h[1][threadIdx.x] +
                       h[2][threadIdx.x] + h[3][threadIdx.x];
    if (t) atomicAdd(&hist[row * 256 + threadIdx.x], t);

    float bs = blockSum(ss);
    if (threadIdx.x == 0) atomicAdd(&sums[1], bs);
}

// ---------------------------------------------------------------------------
// Finalize: entropies + the 4 output scalars
// ---------------------------------------------------------------------------
__global__ __launch_bounds__(256) void k_finalize(
    const unsigned* __restrict__ hist0, const unsigned* __restrict__ hist1,
    const float* __restrict__ sums, float* __restrict__ out)
{
    float e0 = 0.f, e1 = 0.f;
    for (int i = threadIdx.x; i < 48 * 256; i += 256) {
        float p0 = (float)hist0[i] * (1.0f / HWSZ);
        if (p0 > 0.f) e0 -= p0 * log2f(p0);
        float p1 = (float)hist1[i] * (1.0f / HWSZ);
        if (p1 > 0.f) e1 -= p1 * log2f(p1);
    }
    float t0 = blockSum(e0);
    float t1 = blockSum(e1);
    if (threadIdx.x == 0) {
        const float N = (float)BATCH * 3.f * (float)HWSZ;
        out[0] = 128.f * sqrtf(sums[1] / N);   // loss1 (deltas)
        out[1] = 128.f * sqrtf(sums[0] / N);   // loss0 (x)
        out[2] = t0 * (1.f / (8.f * 48.f));    // invcr0
        out[3] = t1 * (1.f / (8.f * 48.f));    // invcr1
    }
}

// ---------------------------------------------------------------------------
extern "C" void kernel_launch(void* const* d_in, const int* in_sizes, int n_in,
                              void* d_out, int out_size, void* d_ws, size_t ws_size,
                              hipStream_t stream) {
    const float* x = (const float*)d_in[0];
    const float* w[8];
    const float* bs[8];
    for (int i = 0; i < 8; ++i) {
        w[i]  = (const float*)d_in[1 + 2 * i];
        bs[i] = (const float*)d_in[2 + 2 * i];
    }

    // Fixed region: planes (50.33 MB) + hists + sums; ONE act buffer
    // (8.39 MB/batch) sized adaptively -> chunk = 16 at ws_size = 256 MiB.
    char* ws = (char*)d_ws;
    size_t o = 0;
    float* rpl = (float*)(ws + o); o += (size_t)BATCH * HWSZ * 4;
    float* gpl = (float*)(ws + o); o += (size_t)BATCH * HWSZ * 4;
    float* bpl = (float*)(ws + o); o += (size_t)BATCH * HWSZ * 4;
    unsigned* hist0 = (unsigned*)(ws + o); o += 48 * 256 * 4;
    unsigned* hist1 = (unsigned*)(ws + o); o += 48 * 256 * 4;
    float* sums = (float*)(ws + o); o += 256;

    const size_t actElems = (size_t)16 * HWSZ;          // shorts per batch
    const size_t perBatchBytes = actElems * 2;          // single buffer
    int chunk = 1;
    if (ws_size > o) {
        size_t c = (ws_size - o) / perBatchBytes;
        chunk = (c < 1) ? 1 : (c > BATCH ? BATCH : (int)c);
    }
    short* actA = (short*)(ws + o);

    hipMemsetAsync(hist0, 0, 48 * 256 * 4 * 2 + 256, stream);

    auto predictor = [&](const float* pa, long long sa, const float* pb, long long sb,
                         const float* xs, float* outp) {
        for (int b0 = 0; b0 < BATCH; b0 += chunk) {
            const int zc = (BATCH - b0 < chunk) ? (BATCH - b0) : chunk;
            const dim3 gq(WW / 64, HH / STRIPH, zc);
            k_quadA<<<gq, 256, 0, stream>>>(
                pa + (long long)b0 * sa, sa, pb + (long long)b0 * sb, sb,
                actA, w[0], bs[0], w[1], bs[1], w[2], bs[2], w[3], bs[3]);
            k_quadB<<<gq, 256, 0, stream>>>(
                actA, xs + (long long)b0 * 3 * HWSZ, 3LL * HWSZ,
                outp + (long long)b0 * HWSZ,
                w[4], bs[4], w[5], bs[5], w[6], bs[6], w[7], bs[7]);
        }
    };

    // r = x_r - pred(g, b);  g = x_g - pred(r, b);  b = x_b - pred(r, g)
    predictor(x + 1LL * HWSZ, 3LL * HWSZ, x + 2LL * HWSZ, 3LL * HWSZ,
              x + 0LL * HWSZ, rpl);
    predictor(rpl, (long long)HWSZ, x + 2LL * HWSZ, 3LL * HWSZ,
              x + 1LL * HWSZ, gpl);
    predictor(rpl, (long long)HWSZ, gpl, (long long)HWSZ,
              x + 2LL * HWSZ, bpl);

    const dim3 sgrid(64, 48);
    k_stats_x<<<sgrid, 256, 0, stream>>>(x, hist0, sums);
    const dim3 dgrid(64, BATCH, 3);
    k_stats_delta<<<dgrid, 256, 0, stream>>>(rpl, hist1, sums);

    k_finalize<<<1, 256, 0, stream>>>(hist0, hist1, sums, (float*)d_out);
}

// Round 20
// 1580.158 us; speedup vs baseline: 1.5448x; 1.5448x over previous
//
#include <hip/hip_runtime.h>
#include <hip/hip_bf16.h>

typedef __hip_bfloat16 hbf16;
typedef __attribute__((ext_vector_type(8))) short bfrag8;
typedef __attribute__((ext_vector_type(4))) short short4v;
typedef __attribute__((ext_vector_type(4))) float f32x4;

#define BATCH 16
#define HH 512
#define WW 512
#define HWSZ (HH * WW)
#define STRIPH 64
#define NSTEP (STRIPH / 4)

__device__ __forceinline__ short f2bf(float f) {
    hbf16 h = __float2bfloat16(f);
    return *(short*)&h;
}

// circular slot in a 6-row window (r >= -5 always; +600 keeps it positive)
__device__ __forceinline__ int slot6(int r) { return (r + 600) % 6; }

__device__ __forceinline__ float blockSum(float v) {
#pragma unroll
    for (int o = 32; o > 0; o >>= 1) v += __shfl_down(v, o, 64);
    __shared__ float sh[4];
    const int lane = threadIdx.x & 63, wid = threadIdx.x >> 6;
    if (lane == 0) sh[wid] = v;
    __syncthreads();
    float r = 0.f;
    if (threadIdx.x == 0) r = sh[0] + sh[1] + sh[2] + sh[3];
    __syncthreads();
    return r;
}

// Generic conv16 row into a 6-slot LDS window. Captures: lx, cib, c0, tx0,
// dys, dxs. AF must be a named bfrag8[5] (stays in regs).
#define CONV_ROW(INW, IW, OUTW, OW, AF, B0_, B1_, B2_, B3_, GR) do {          \
    const int gr_ = (GR);                                                      \
    const bool rok_ = ((unsigned)gr_ < (unsigned)HH);                          \
    const int halo_ = ((OW) - 64) / 2;                                         \
    const int rslot_ = slot6(gr_) * (OW);                                      \
    const int rm1_ = slot6(gr_ - 1) * (IW);                                    \
    const int r00_ = slot6(gr_) * (IW);                                        \
    const int rp1_ = slot6(gr_ + 1) * (IW);                                    \
    _Pragma("unroll")                                                          \
    for (int c_ = 0; c_ < 5; ++c_) {                                           \
        const int xr_ = c_ * 16 + lx;                                          \
        const int xc_ = (xr_ < (OW)) ? xr_ : ((OW) - 1);                       \
        f32x4 a_ = { B0_, B1_, B2_, B3_ };                                     \
        _Pragma("unroll")                                                      \
        for (int s_ = 0; s_ < 5; ++s_) {                                       \
            const int rof_ = (dys[s_] == 0) ? rm1_ : ((dys[s_] == 2) ? rp1_ : r00_); \
            const bfrag8 q_ = *(const bfrag8*)&(INW)[(rof_ + (xc_ + dxs[s_])) * 16 + cib]; \
            a_ = __builtin_amdgcn_mfma_f32_16x16x32_bf16(AF[s_], q_, a_, 0, 0, 0); \
        }                                                                      \
        if (xr_ < (OW)) {                                                      \
            const int gx_ = tx0 - halo_ + xr_;                                 \
            const bool ok_ = rok_ && ((unsigned)gx_ < (unsigned)WW);           \
            short4v st_;                                                       \
            _Pragma("unroll")                                                  \
            for (int i_ = 0; i_ < 4; ++i_) {                                   \
                float r_ = a_[i_]; r_ = (r_ >= 0.f) ? r_ : 0.01f * r_;         \
                st_[i_] = ok_ ? f2bf(r_) : (short)0;                           \
            }                                                                  \
            *(short4v*)&(OUTW)[(rslot_ + xr_) * 16 + c0] = st_;                \
        }                                                                      \
    }                                                                          \
} while (0)

// ---------------------------------------------------------------------------
// quadA: L0(2ch fp32 -> 16) + L1 + L2 + L3, rolling 6-slot windows over a
// 64x64 strip. Windows: fin 72w(2ch), a0 70w, a1 68w, a2 66w = 40.9 KB ->
// 3 blocks/CU (no VGPR cap: weight frags must stay in registers).
// ---------------------------------------------------------------------------
__global__ __launch_bounds__(256) void k_quadA(
    const float* __restrict__ p0, long long s0,
    const float* __restrict__ p1, long long s1,
    short* __restrict__ outA,
    const float* __restrict__ w0, const float* __restrict__ b0,
    const float* __restrict__ w1, const float* __restrict__ b1,
    const float* __restrict__ w2, const float* __restrict__ b2,
    const float* __restrict__ w3, const float* __restrict__ b3)
{
    __shared__ short finW[6 * 72 * 2];     //  1,728 B
    __shared__ short a0W[6 * 70 * 16];     // 13,440 B
    __shared__ short a1W[6 * 68 * 16];     // 13,056 B
    __shared__ short a2W[6 * 66 * 16];     // 12,672 B

    const int tid = threadIdx.x, lane = tid & 63, wv = tid >> 6;
    const int tx0 = blockIdx.x * 64, Y0 = blockIdx.y * STRIPH;
    const long long b = blockIdx.z;
    const float* pa = p0 + b * s0;
    const float* pb = p1 + b * s1;
    short* outb = outA + b * (long long)HWSZ * 16;

    const int arow = lane & 15, grp = lane >> 4, lx = lane & 15;
    const int half = grp & 1, cib = half * 8, kofb = grp >> 1;
    const int c0 = grp * 4;

    bfrag8 a0f;
#pragma unroll
    for (int j = 0; j < 8; ++j) {
        const int k = grp * 8 + j;
        a0f[j] = (k < 18) ? f2bf(w0[arow * 18 + (k & 1) * 9 + (k >> 1)]) : (short)0;
    }
    bfrag8 af1[5], af2[5], af3[5];
    int dys[5], dxs[5];
#pragma unroll
    for (int s = 0; s < 5; ++s) {
        const int koff = 2 * s + kofb;
        const int kc = (koff < 9) ? koff : 8;
        dys[s] = kc / 3; dxs[s] = kc - dys[s] * 3;
#pragma unroll
        for (int j = 0; j < 8; ++j) {
            af1[s][j] = (koff < 9) ? f2bf(w1[(arow * 16 + cib + j) * 9 + koff]) : (short)0;
            af2[s][j] = (koff < 9) ? f2bf(w2[(arow * 16 + cib + j) * 9 + koff]) : (short)0;
            af3[s][j] = (koff < 9) ? f2bf(w3[(arow * 16 + cib + j) * 9 + koff]) : (short)0;
        }
    }
    const float b00 = b0[c0], b01 = b0[c0 + 1], b02 = b0[c0 + 2], b03 = b0[c0 + 3];
    const float b10 = b1[c0], b11 = b1[c0 + 1], b12 = b1[c0 + 2], b13 = b1[c0 + 3];
    const float b20 = b2[c0], b21 = b2[c0 + 1], b22 = b2[c0 + 2], b23 = b2[c0 + 3];
    const float b30 = b3[c0], b31 = b3[c0 + 1], b32 = b3[c0 + 2], b33 = b3[c0 + 3];

    auto STAGE = [&](int r0, int nr) {
        const int tot = nr * 144;   // 72 px x 2 ch
        for (int i = tid; i < tot; i += 256) {
            const int rr = i / 144, rem = i - rr * 144, xx = rem >> 1, ci = rem & 1;
            const int gr = r0 + rr, gx = tx0 - 4 + xx;
            float v = 0.f;
            if ((unsigned)gr < (unsigned)HH && (unsigned)gx < (unsigned)WW)
                v = (ci ? pb : pa)[gr * WW + gx];
            finW[(slot6(gr) * 72 + xx) * 2 + ci] = f2bf(v);
        }
    };

    auto L0ROW = [&](int gr) {   // a0 row gr, width 70, out base tx0-3
        const bool rok = ((unsigned)gr < (unsigned)HH);
        const int rslot = slot6(gr) * 70;
        const int rm1 = slot6(gr - 1) * 72, r00 = slot6(gr) * 72, rp1 = slot6(gr + 1) * 72;
#pragma unroll
        for (int c = 0; c < 5; ++c) {
            const int xr = c * 16 + lx;
            const int xc = (xr < 70) ? xr : 69;
            bfrag8 bf;
#pragma unroll
            for (int j = 0; j < 8; ++j) {
                const int k = grp * 8 + j;
                short v = 0;
                if (k < 18) {
                    const int tap = k >> 1, dy = tap / 3, dx = tap - dy * 3;
                    const int ro = (dy == 0) ? rm1 : ((dy == 2) ? rp1 : r00);
                    v = finW[(ro + (xc + dx)) * 2 + (k & 1)];
                }
                bf[j] = v;
            }
            f32x4 a = { b00, b01, b02, b03 };
            a = __builtin_amdgcn_mfma_f32_16x16x32_bf16(a0f, bf, a, 0, 0, 0);
            if (xr < 70) {
                const int gx = tx0 - 3 + xr;
                const bool ok = rok && ((unsigned)gx < (unsigned)WW);
                short4v st;
#pragma unroll
                for (int i = 0; i < 4; ++i) {
                    float r = a[i]; r = (r >= 0.f) ? r : 0.01f * r;
                    st[i] = ok ? f2bf(r) : (short)0;
                }
                *(short4v*)&a0W[(rslot + xr) * 16 + c0] = st;
            }
        }
    };

    auto OUT3 = [&](int gr) {    // rows/cols always in-image
        const int rm1 = slot6(gr - 1) * 66, r00 = slot6(gr) * 66, rp1 = slot6(gr + 1) * 66;
#pragma unroll
        for (int c = 0; c < 4; ++c) {
            const int o = c * 16 + lx;
            f32x4 a = { b30, b31, b32, b33 };
#pragma unroll
            for (int s = 0; s < 5; ++s) {
                const int rof = (dys[s] == 0) ? rm1 : ((dys[s] == 2) ? rp1 : r00);
                const bfrag8 q = *(const bfrag8*)&a2W[(rof + (o + dxs[s])) * 16 + cib];
                a = __builtin_amdgcn_mfma_f32_16x16x32_bf16(af3[s], q, a, 0, 0, 0);
            }
            short4v st;
#pragma unroll
            for (int i = 0; i < 4; ++i) {
                float r = a[i];
                st[i] = f2bf(r >= 0.f ? r : 0.01f * r);
            }
            *(short4v*)&outb[((long long)gr * WW + tx0 + o) * 16 + c0] = st;
        }
    };

    // prologue (6-slot constrained)
    STAGE(Y0 - 4, 6);                       // rows Y0-4..Y0+1
    __syncthreads();
    L0ROW(Y0 - 3 + wv);                     // a0 rows Y0-3..Y0
    __syncthreads();
    STAGE(Y0 + 2, 2);                       // rows Y0+2,Y0+3
    __syncthreads();
    if (wv < 2) L0ROW(Y0 + 1 + wv);         // a0 rows Y0+1,Y0+2
    __syncthreads();
    CONV_ROW(a0W, 70, a1W, 68, af1, b10, b11, b12, b13, Y0 - 2 + wv);
    __syncthreads();
    if (wv < 2) CONV_ROW(a1W, 68, a2W, 66, af2, b20, b21, b22, b23, Y0 - 1 + wv);
    __syncthreads();

    for (int k = 0; k < NSTEP; ++k) {
        const int base = Y0 + 4 * k;
        STAGE(base + 4, 4);
        __syncthreads();
        L0ROW(base + 3 + wv);
        __syncthreads();
        CONV_ROW(a0W, 70, a1W, 68, af1, b10, b11, b12, b13, base + 2 + wv);
        __syncthreads();
        CONV_ROW(a1W, 68, a2W, 66, af2, b20, b21, b22, b23, base + 1 + wv);
        __syncthreads();
        OUT3(base + wv);
    }
}

// ---------------------------------------------------------------------------
// quadB: L4 + L5 + L6 + L7(clip/median3/subtract), 6-slot rolling windows.
// Windows: in 72w, a4 70w, a5 68w, a6 66w (16ch) = 52.9 KB -> 3 blocks/CU.
// ---------------------------------------------------------------------------
__global__ __launch_bounds__(256) void k_quadB(
    const short* __restrict__ inA,
    const float* __restrict__ xsrc, long long xstride,
    float* __restrict__ outp,
    const float* __restrict__ w4, const float* __restrict__ b4,
    const float* __restrict__ w5, const float* __restrict__ b5,
    const float* __restrict__ w6, const float* __restrict__ b6,
    const float* __restrict__ w7, const float* __restrict__ b7)
{
    __shared__ short inW[6 * 72 * 16];    // 13,824 B
    __shared__ short a4W[6 * 70 * 16];    // 13,440 B
    __shared__ short a5W[6 * 68 * 16];    // 13,056 B
    __shared__ short a6W[6 * 66 * 16];    // 12,672 B

    const int tid = threadIdx.x, lane = tid & 63, wv = tid >> 6;
    const int tx0 = blockIdx.x * 64, Y0 = blockIdx.y * STRIPH;
    const long long b = blockIdx.z;
    const short* inb = inA + b * (long long)HWSZ * 16;
    const float* xb = xsrc + b * xstride;
    float* ob = outp + b * (long long)HWSZ;

    const int arow = lane & 15, grp = lane >> 4, lx = lane & 15;
    const int half = grp & 1, cib = half * 8, kofb = grp >> 1;
    const int c0 = grp * 4;

    bfrag8 af4[5], af5[5], af6[5], lf[5];
    int dys[5], dxs[5];
#pragma unroll
    for (int s = 0; s < 5; ++s) {
        const int koff = 2 * s + kofb;
        const int kc = (koff < 9) ? koff : 8;
        dys[s] = kc / 3; dxs[s] = kc - dys[s] * 3;
#pragma unroll
        for (int j = 0; j < 8; ++j) {
            af4[s][j] = (koff < 9) ? f2bf(w4[(arow * 16 + cib + j) * 9 + koff]) : (short)0;
            af5[s][j] = (koff < 9) ? f2bf(w5[(arow * 16 + cib + j) * 9 + koff]) : (short)0;
            af6[s][j] = (koff < 9) ? f2bf(w6[(arow * 16 + cib + j) * 9 + koff]) : (short)0;
            lf[s][j]  = (arow < 3 && koff < 9) ? f2bf(w7[(arow * 16 + cib + j) * 9 + koff]) : (short)0;
        }
    }
    const float b40 = b4[c0], b41 = b4[c0 + 1], b42 = b4[c0 + 2], b43 = b4[c0 + 3];
    const float b50 = b5[c0], b51 = b5[c0 + 1], b52 = b5[c0 + 2], b53 = b5[c0 + 3];
    const float b60 = b6[c0], b61 = b6[c0 + 1], b62 = b6[c0 + 2], b63 = b6[c0 + 3];
    const float lb0 = (grp == 0) ? b7[0] : 0.f;
    const float lb1 = (grp == 0) ? b7[1] : 0.f;
    const float lb2 = (grp == 0) ? b7[2] : 0.f;

    auto STAGEB = [&](int r0, int nr) {
        const int tot = nr * 144;   // 72 granules x 2 halves
        for (int i = tid; i < tot; i += 256) {
            const int rr = i / 144, rem = i - rr * 144, ix = rem >> 1, hf = rem & 1;
            const int gr = r0 + rr, gx = tx0 - 4 + ix;
            bfrag8 v = {0, 0, 0, 0, 0, 0, 0, 0};
            if ((unsigned)gr < (unsigned)HH && (unsigned)gx < (unsigned)WW)
                v = *(const bfrag8*)&inb[((long long)gr * WW + gx) * 16 + hf * 8];
            *(bfrag8*)&inW[(slot6(gr) * 72 + ix) * 16 + hf * 8] = v;
        }
    };

    auto OUT7 = [&](int gr) {
        const int rm1 = slot6(gr - 1) * 66, r00 = slot6(gr) * 66, rp1 = slot6(gr + 1) * 66;
#pragma unroll
        for (int c = 0; c < 4; ++c) {
            const int o = c * 16 + lx;
            f32x4 a = { lb0, lb1, lb2, 0.f };
#pragma unroll
            for (int s = 0; s < 5; ++s) {
                const int rof = (dys[s] == 0) ? rm1 : ((dys[s] == 2) ? rp1 : r00);
                const bfrag8 q = *(const bfrag8*)&a6W[(rof + (o + dxs[s])) * 16 + cib];
                a = __builtin_amdgcn_mfma_f32_16x16x32_bf16(lf[s], q, a, 0, 0, 0);
            }
            if (grp == 0) {
                float y0 = fminf(fmaxf(a[0], -1.f), 1.f);
                float y1 = fminf(fmaxf(a[1], -1.f), 1.f);
                float y2 = fminf(fmaxf(a[2], -1.f), 1.f);
                float med = fmaxf(fminf(y0, fmaxf(y1, y2)), fminf(y1, y2));
                const long long pix = (long long)gr * WW + tx0 + o;
                ob[pix] = xb[pix] - med;
            }
        }
    };

    // prologue (6-slot constrained)
    STAGEB(Y0 - 4, 6);
    __syncthreads();
    CONV_ROW(inW, 72, a4W, 70, af4, b40, b41, b42, b43, Y0 - 3 + wv);
    __syncthreads();
    STAGEB(Y0 + 2, 2);
    __syncthreads();
    if (wv < 2) CONV_ROW(inW, 72, a4W, 70, af4, b40, b41, b42, b43, Y0 + 1 + wv);
    __syncthreads();
    CONV_ROW(a4W, 70, a5W, 68, af5, b50, b51, b52, b53, Y0 - 2 + wv);
    __syncthreads();
    if (wv < 2) CONV_ROW(a5W, 68, a6W, 66, af6, b60, b61, b62, b63, Y0 - 1 + wv);
    __syncthreads();

    for (int k = 0; k < NSTEP; ++k) {
        const int base = Y0 + 4 * k;
        STAGEB(base + 4, 4);
        __syncthreads();
        CONV_ROW(inW, 72, a4W, 70, af4, b40, b41, b42, b43, base + 3 + wv);
        __syncthreads();
        CONV_ROW(a4W, 70, a5W, 68, af5, b50, b51, b52, b53, base + 2 + wv);
        __syncthreads();
        CONV_ROW(a5W, 68, a6W, 66, af6, b60, b61, b62, b63, base + 1 + wv);
        __syncthreads();
        OUT7(base + wv);
    }
}

// ---------------------------------------------------------------------------
// Stats over x: float4 loads, per-wave LDS histograms, SSQ
// ---------------------------------------------------------------------------
__global__ __launch_bounds__(256) void k_stats_x(
    const float* __restrict__ x, unsigned* __restrict__ hist, float* __restrict__ sums)
{
    const int p = blockIdx.y;
    const f32x4* src = (const f32x4*)(x + (long long)p * HWSZ);
    __shared__ unsigned h[4][256];
    for (int i = threadIdx.x; i < 1024; i += 256) ((unsigned*)h)[i] = 0;
    __syncthreads();
    const int wid = threadIdx.x >> 6;

    float ss = 0.f;
    for (int i4 = blockIdx.x * 256 + threadIdx.x; i4 < HWSZ / 4; i4 += gridDim.x * 256) {
        const f32x4 v4 = src[i4];
#pragma unroll
        for (int e = 0; e < 4; ++e) {
            const float v = v4[e];
            ss += v * v;
            if (v >= -1.f && v <= 1.f) {
                int idx = (int)floorf((v + 1.f) * 128.f);
                idx = min(max(idx, 0), 255);
                atomicAdd(&h[wid][idx], 1u);
            }
        }
    }
    __syncthreads();
    const unsigned t = h[0][threadIdx.x] + h[1][threadIdx.x] +
                       h[2][threadIdx.x] + h[3][threadIdx.x];
    if (t) atomicAdd(&hist[p * 256 + threadIdx.x], t);

    float bs = blockSum(ss);
    if (threadIdx.x == 0) atomicAdd(&sums[0], bs);
}

// ---------------------------------------------------------------------------
// Stats over deltas, all 3 planes in one dispatch (z = channel).
// ---------------------------------------------------------------------------
__global__ __launch_bounds__(256) void k_stats_delta(
    const float* __restrict__ planes,
    unsigned* __restrict__ hist, float* __restrict__ sums)
{
    const int b = blockIdx.y, cz = blockIdx.z;
    const float* P = planes + ((long long)cz * BATCH + b) * HWSZ;
    const int row = b * 3 + cz;
    __shared__ unsigned h[4][256];
    for (int i = threadIdx.x; i < 1024; i += 256) ((unsigned*)h)[i] = 0;
    __syncthreads();
    const int wid = threadIdx.x >> 6;

    float ss = 0.f;
    for (int i4 = blockIdx.x * 256 + threadIdx.x; i4 < HWSZ / 4; i4 += gridDim.x * 256) {
        const int i0 = i4 * 4;
        const int y = i0 >> 9, x0 = i0 & (WW - 1);
        const f32x4 cur = ((const f32x4*)P)[i4];
        f32x4 up = { 0.f, 0.f, 0.f, 0.f };
        if (y) up = ((const f32x4*)P)[i4 - (WW / 4)];
        const float left = x0 ? P[i0 - 1] : 0.f;
        const float upl = (x0 && y) ? P[i0 - WW - 1] : 0.f;
#pragma unroll
        for (int e = 0; e < 4; ++e) {
            const float v = cur[e];
            const float n = up[e];
            const float wv = e ? cur[e - 1] : left;
            const float nw = e ? up[e - 1] : upl;
            float pr = n + wv - nw;
            pr = fminf(fmaxf(pr, fminf(n, wv)), fmaxf(n, wv));
            const float d = v - pr;
            ss += d * d;
            if (d >= -1.f && d <= 1.f) {
                int idx = (int)floorf((d + 1.f) * 128.f);
                idx = min(max(idx, 0), 255);
                atomicAdd(&h[wid][idx], 1u);
            }
        }
    }
    __syncthreads();
    const unsigned t = h[0][threadIdx.x] + h[1][threadIdx.x] +
                       h[2][threadIdx.x] + h[3][threadIdx.x];
    if (t) atomicAdd(&hist[row * 256 + threadIdx.x], t);

    float bs = blockSum(ss);
    if (threadIdx.x == 0) atomicAdd(&sums[1], bs);
}

// ---------------------------------------------------------------------------
// Finalize: entropies + the 4 output scalars
// ---------------------------------------------------------------------------
__global__ __launch_bounds__(256) void k_finalize(
    const unsigned* __restrict__ hist0, const unsigned* __restrict__ hist1,
    const float* __restrict__ sums, float* __restrict__ out)
{
    float e0 = 0.f, e1 = 0.f;
    for (int i = threadIdx.x; i < 48 * 256; i += 256) {
        float p0 = (float)hist0[i] * (1.0f / HWSZ);
        if (p0 > 0.f) e0 -= p0 * log2f(p0);
        float p1 = (float)hist1[i] * (1.0f / HWSZ);
        if (p1 > 0.f) e1 -= p1 * log2f(p1);
    }
    float t0 = blockSum(e0);
    float t1 = blockSum(e1);
    if (threadIdx.x == 0) {
        const float N = (float)BATCH * 3.f * (float)HWSZ;
        out[0] = 128.f * sqrtf(sums[1] / N);   // loss1 (deltas)
        out[1] = 128.f * sqrtf(sums[0] / N);   // loss0 (x)
        out[2] = t0 * (1.f / (8.f * 48.f));    // invcr0
        out[3] = t1 * (1.f / (8.f * 48.f));    // invcr1
    }
}

// ---------------------------------------------------------------------------
extern "C" void kernel_launch(void* const* d_in, const int* in_sizes, int n_in,
                              void* d_out, int out_size, void* d_ws, size_t ws_size,
                              hipStream_t stream) {
    const float* x = (const float*)d_in[0];
    const float* w[8];
    const float* bs[8];
    for (int i = 0; i < 8; ++i) {
        w[i]  = (const float*)d_in[1 + 2 * i];
        bs[i] = (const float*)d_in[2 + 2 * i];
    }

    // Fixed region: planes (50.33 MB) + hists + sums; ONE act buffer
    // (8.39 MB/batch) sized adaptively -> chunk = 16 at ws_size = 256 MiB.
    char* ws = (char*)d_ws;
    size_t o = 0;
    float* rpl = (float*)(ws + o); o += (size_t)BATCH * HWSZ * 4;
    float* gpl = (float*)(ws + o); o += (size_t)BATCH * HWSZ * 4;
    float* bpl = (float*)(ws + o); o += (size_t)BATCH * HWSZ * 4;
    unsigned* hist0 = (unsigned*)(ws + o); o += 48 * 256 * 4;
    unsigned* hist1 = (unsigned*)(ws + o); o += 48 * 256 * 4;
    float* sums = (float*)(ws + o); o += 256;

    const size_t actElems = (size_t)16 * HWSZ;          // shorts per batch
    const size_t perBatchBytes = actElems * 2;          // single buffer
    int chunk = 1;
    if (ws_size > o) {
        size_t c = (ws_size - o) / perBatchBytes;
        chunk = (c < 1) ? 1 : (c > BATCH ? BATCH : (int)c);
    }
    short* actA = (short*)(ws + o);

    hipMemsetAsync(hist0, 0, 48 * 256 * 4 * 2 + 256, stream);

    auto predictor = [&](const float* pa, long long sa, const float* pb, long long sb,
                         const float* xs, float* outp) {
        for (int b0 = 0; b0 < BATCH; b0 += chunk) {
            const int zc = (BATCH - b0 < chunk) ? (BATCH - b0) : chunk;
            const dim3 gq(WW / 64, HH / STRIPH, zc);
            k_quadA<<<gq, 256, 0, stream>>>(
                pa + (long long)b0 * sa, sa, pb + (long long)b0 * sb, sb,
                actA, w[0], bs[0], w[1], bs[1], w[2], bs[2], w[3], bs[3]);
            k_quadB<<<gq, 256, 0, stream>>>(
                actA, xs + (long long)b0 * 3 * HWSZ, 3LL * HWSZ,
                outp + (long long)b0 * HWSZ,
                w[4], bs[4], w[5], bs[5], w[6], bs[6], w[7], bs[7]);
        }
    };

    // r = x_r - pred(g, b);  g = x_g - pred(r, b);  b = x_b - pred(r, g)
    predictor(x + 1LL * HWSZ, 3LL * HWSZ, x + 2LL * HWSZ, 3LL * HWSZ,
              x + 0LL * HWSZ, rpl);
    predictor(rpl, (long long)HWSZ, x + 2LL * HWSZ, 3LL * HWSZ,
              x + 1LL * HWSZ, gpl);
    predictor(rpl, (long long)HWSZ, gpl, (long long)HWSZ,
              x + 2LL * HWSZ, bpl);

    const dim3 sgrid(64, 48);
    k_stats_x<<<sgrid, 256, 0, stream>>>(x, hist0, sums);
    const dim3 dgrid(64, BATCH, 3);
    k_stats_delta<<<dgrid, 256, 0, stream>>>(rpl, hist1, sums);

    k_finalize<<<1, 256, 0, stream>>>(hist0, hist1, sums, (float*)d_out);
}

// Round 21
// 1307.603 us; speedup vs baseline: 1.8668x; 1.2084x over previous
//
#include <hip/hip_runtime.h>
#include <hip/hip_bf16.h>

typedef __hip_bfloat16 hbf16;
typedef __attribute__((ext_vector_type(8))) short bfrag8;
typedef __attribute__((ext_vector_type(4))) short short4v;
typedef __attribute__((ext_vector_type(4))) float f32x4;

#define BATCH 16
#define HH 512
#define WW 512
#define HWSZ (HH * WW)

__device__ __forceinline__ short f2bf(float f) {
    hbf16 h = __float2bfloat16(f);
    return *(short*)&h;
}

__device__ __forceinline__ float blockSum(float v) {
#pragma unroll
    for (int o = 32; o > 0; o >>= 1) v += __shfl_down(v, o, 64);
    __shared__ float sh[4];
    const int lane = threadIdx.x & 63, wid = threadIdx.x >> 6;
    if (lane == 0) sh[wid] = v;
    __syncthreads();
    float r = 0.f;
    if (threadIdx.x == 0) r = sh[0] + sh[1] + sh[2] + sh[3];
    __syncthreads();
    return r;
}

// ---------------------------------------------------------------------------
// Full 8-layer predictor, software-pipelined: 512 thr = 8 waves, wave w owns
// layer w (wave 7 also stages input + runs the L7/clip/median3/subtract
// epilogue). One barrier per step; skew = 2 rows/layer.
//   step S: stage fin row Y0-8+S (S<80); layer l row = Y0-10+S-2l.
//   Newest dependency (row+1 of window l-1) written at step S-1  -> safe.
//   4-slot windows (slot = row & 3): reuse at +4 steps > last read at +3.
// Windows: fin 4x80x2ch; a_l (l=0..6) 4 x (78-2l) x 16ch, packed in aW at
// offset 64*l*(79-l) shorts. LDS 65.8 KB -> 2 blocks/CU (16 waves).
// MFMA fragment mapping identical to the R13/R18-verified kernels.
// ---------------------------------------------------------------------------
__global__ __launch_bounds__(512) void k_pred8(
    const float* __restrict__ p0, long long s0,
    const float* __restrict__ p1, long long s1,
    const float* __restrict__ xsrc, long long xstride,
    float* __restrict__ outp,
    const float* __restrict__ w0, const float* __restrict__ b0,
    const float* __restrict__ w1, const float* __restrict__ b1,
    const float* __restrict__ w2, const float* __restrict__ b2,
    const float* __restrict__ w3, const float* __restrict__ b3,
    const float* __restrict__ w4, const float* __restrict__ b4,
    const float* __restrict__ w5, const float* __restrict__ b5,
    const float* __restrict__ w6, const float* __restrict__ b6,
    const float* __restrict__ w7, const float* __restrict__ b7)
{
    __shared__ short finW[4 * 80 * 2];     //  1,280 B
    __shared__ short aW[4 * 504 * 16];     // 64,512 B (a0..a6 packed)

    const int tid = threadIdx.x, lane = tid & 63, wv = tid >> 6;
    const int tx0 = blockIdx.x * 64, Y0 = blockIdx.y * 64;
    const long long b = blockIdx.z;
    const float* pa = p0 + b * s0;
    const float* pb = p1 + b * s1;
    const float* xb = xsrc + b * xstride;
    float* ob = outp + b * (long long)HWSZ;

    const int arow = lane & 15, grp = lane >> 4, lx = lane & 15;
    const int cib = (grp & 1) * 8, kofb = grp >> 1;
    const int c0 = grp * 4;

    // per-wave window geometry (layer wv): in = window wv-1, out = window wv
    const short* inw = aW + 64 * (wv - 1) * (80 - wv);   // valid for wv>=1
    short* outw = aW + 64 * wv * (79 - wv);              // valid for wv<=6
    const int IW = 80 - 2 * wv, OW = 78 - 2 * wv;

    // per-wave weight fragments + tap offsets
    bfrag8 myf[5];
    int dys[5], dxs[5];
    float mb0 = 0.f, mb1 = 0.f, mb2 = 0.f, mb3 = 0.f;
#pragma unroll
    for (int s = 0; s < 5; ++s) {
        const int koff = 2 * s + kofb;
        const int kc = (koff < 9) ? koff : 8;
        dys[s] = kc / 3; dxs[s] = kc - dys[s] * 3;
#pragma unroll
        for (int j = 0; j < 8; ++j) myf[s][j] = 0;
    }
    if (wv == 0) {
        // L0: K=18 gather fragment lives in myf[0]
#pragma unroll
        for (int j = 0; j < 8; ++j) {
            const int k = grp * 8 + j;
            myf[0][j] = (k < 18) ? f2bf(w0[arow * 18 + (k & 1) * 9 + (k >> 1)])
                                 : (short)0;
        }
        mb0 = b0[c0]; mb1 = b0[c0 + 1]; mb2 = b0[c0 + 2]; mb3 = b0[c0 + 3];
    } else {
        const float* wp = (wv == 1) ? w1 : (wv == 2) ? w2 : (wv == 3) ? w3 :
                          (wv == 4) ? w4 : (wv == 5) ? w5 : (wv == 6) ? w6 : w7;
        const float* bp = (wv == 1) ? b1 : (wv == 2) ? b2 : (wv == 3) ? b3 :
                          (wv == 4) ? b4 : (wv == 5) ? b5 : (wv == 6) ? b6 : b7;
        const bool rmask = (wv < 7) || (arow < 3);
#pragma unroll
        for (int s = 0; s < 5; ++s) {
            const int koff = 2 * s + kofb;
#pragma unroll
            for (int j = 0; j < 8; ++j)
                myf[s][j] = (rmask && koff < 9)
                              ? f2bf(wp[(arow * 16 + cib + j) * 9 + koff])
                              : (short)0;
        }
        if (wv == 7) {
            mb0 = (grp == 0) ? bp[0] : 0.f;
            mb1 = (grp == 0) ? bp[1] : 0.f;
            mb2 = (grp == 0) ? bp[2] : 0.f;
        } else {
            mb0 = bp[c0]; mb1 = bp[c0 + 1]; mb2 = bp[c0 + 2]; mb3 = bp[c0 + 3];
        }
    }

    // generic conv row (layers 1..6): inw/IW -> outw/OW, global row gr
    auto CONVG = [&](int gr) {
        const bool rok = ((unsigned)gr < (unsigned)HH);
        const int halo = (OW - 64) >> 1;
        const int rslot = (gr & 3) * OW;
        const int rm1 = ((gr - 1) & 3) * IW, r00 = (gr & 3) * IW,
                  rp1 = ((gr + 1) & 3) * IW;
#pragma unroll
        for (int c = 0; c < 5; ++c) {
            const int xr = c * 16 + lx;
            const int xc = (xr < OW) ? xr : (OW - 1);
            f32x4 a = { mb0, mb1, mb2, mb3 };
#pragma unroll
            for (int s = 0; s < 5; ++s) {
                const int rof = (dys[s] == 0) ? rm1 : ((dys[s] == 2) ? rp1 : r00);
                const bfrag8 q = *(const bfrag8*)&inw[(rof + xc + dxs[s]) * 16 + cib];
                a = __builtin_amdgcn_mfma_f32_16x16x32_bf16(myf[s], q, a, 0, 0, 0);
            }
            if (xr < OW) {
                const int gx = tx0 - halo + xr;
                const bool ok = rok && ((unsigned)gx < (unsigned)WW);
                short4v st;
#pragma unroll
                for (int i = 0; i < 4; ++i) {
                    float r = a[i]; r = (r >= 0.f) ? r : 0.01f * r;
                    st[i] = ok ? f2bf(r) : (short)0;
                }
                *(short4v*)&outw[(rslot + xr) * 16 + c0] = st;
            }
        }
    };

    // L0 row (wave 0): fin gather (K=18) -> a0 (width 78, halo 7)
    auto L0ROW = [&](int gr) {
        const bool rok = ((unsigned)gr < (unsigned)HH);
        const int rslot = (gr & 3) * 78;
        const int rm1 = ((gr - 1) & 3) * 80, r00 = (gr & 3) * 80,
                  rp1 = ((gr + 1) & 3) * 80;
        short* a0w = aW;   // window 0 at offset 0
#pragma unroll
        for (int c = 0; c < 5; ++c) {
            const int xr = c * 16 + lx;
            const int xc = (xr < 78) ? xr : 77;
            bfrag8 bf;
#pragma unroll
            for (int j = 0; j < 8; ++j) {
                const int k = grp * 8 + j;
                short v = 0;
                if (k < 18) {
                    const int tap = k >> 1, dy = tap / 3, dx = tap - dy * 3;
                    const int ro = (dy == 0) ? rm1 : ((dy == 2) ? rp1 : r00);
                    v = finW[(ro + xc + dx) * 2 + (k & 1)];
                }
                bf[j] = v;
            }
            f32x4 a = { mb0, mb1, mb2, mb3 };
            a = __builtin_amdgcn_mfma_f32_16x16x32_bf16(myf[0], bf, a, 0, 0, 0);
            if (xr < 78) {
                const int gx = tx0 - 7 + xr;
                const bool ok = rok && ((unsigned)gx < (unsigned)WW);
                short4v st;
#pragma unroll
                for (int i = 0; i < 4; ++i) {
                    float r = a[i]; r = (r >= 0.f) ? r : 0.01f * r;
                    st[i] = ok ? f2bf(r) : (short)0;
                }
                *(short4v*)&a0w[(rslot + xr) * 16 + c0] = st;
            }
        }
    };

    // L7 row (wave 7): a6 (width 66) -> clip/median3/(x - med) -> global
    auto OUT7 = [&](int gr) {
        const int rm1 = ((gr - 1) & 3) * 66, r00 = (gr & 3) * 66,
                  rp1 = ((gr + 1) & 3) * 66;
#pragma unroll
        for (int c = 0; c < 4; ++c) {
            const int o = c * 16 + lx;
            f32x4 a = { mb0, mb1, mb2, 0.f };
#pragma unroll
            for (int s = 0; s < 5; ++s) {
                const int rof = (dys[s] == 0) ? rm1 : ((dys[s] == 2) ? rp1 : r00);
                const bfrag8 q = *(const bfrag8*)&inw[(rof + o + dxs[s]) * 16 + cib];
                a = __builtin_amdgcn_mfma_f32_16x16x32_bf16(myf[s], q, a, 0, 0, 0);
            }
            if (grp == 0) {
                float y0 = fminf(fmaxf(a[0], -1.f), 1.f);
                float y1 = fminf(fmaxf(a[1], -1.f), 1.f);
                float y2 = fminf(fmaxf(a[2], -1.f), 1.f);
                float med = fmaxf(fminf(y0, fmaxf(y1, y2)), fminf(y1, y2));
                const long long pix = (long long)gr * WW + tx0 + o;
                ob[pix] = xb[pix] - med;
            }
        }
    };

    // main pipeline: 88 steps, ONE barrier each
    for (int S = 0; S < 88; ++S) {
        if (wv == 7) {
            // issue stage loads first (latency hides under OUT7)
            const int R = Y0 - 8 + S;
            const bool doStage = (S < 80);
            float v0 = 0.f, v1 = 0.f, v2 = 0.f;
            if (doStage) {
                const int i0 = lane, i1 = lane + 64, i2 = lane + 128;
                {
                    const int xx = i0 >> 1, ci = i0 & 1, gx = tx0 - 8 + xx;
                    if ((unsigned)R < (unsigned)HH && (unsigned)gx < (unsigned)WW)
                        v0 = (ci ? pb : pa)[R * WW + gx];
                }
                {
                    const int xx = i1 >> 1, ci = i1 & 1, gx = tx0 - 8 + xx;
                    if ((unsigned)R < (unsigned)HH && (unsigned)gx < (unsigned)WW)
                        v1 = (ci ? pb : pa)[R * WW + gx];
                }
                if (i2 < 160) {
                    const int xx = i2 >> 1, ci = i2 & 1, gx = tx0 - 8 + xx;
                    if ((unsigned)R < (unsigned)HH && (unsigned)gx < (unsigned)WW)
                        v2 = (ci ? pb : pa)[R * WW + gx];
                }
            }
            const int r7 = Y0 - 24 + S;
            if (r7 >= Y0 && r7 <= Y0 + 63) OUT7(r7);
            if (doStage) {
                const int base = (R & 3) * 80;
                const int i0 = lane, i1 = lane + 64, i2 = lane + 128;
                finW[(base + (i0 >> 1)) * 2 + (i0 & 1)] = f2bf(v0);
                finW[(base + (i1 >> 1)) * 2 + (i1 & 1)] = f2bf(v1);
                if (i2 < 160)
                    finW[(base + (i2 >> 1)) * 2 + (i2 & 1)] = f2bf(v2);
            }
        } else if (wv == 0) {
            const int r0 = Y0 - 10 + S;
            if (r0 >= Y0 - 7 && r0 <= Y0 + 70) L0ROW(r0);
        } else {
            const int r = Y0 - 10 + S - 2 * wv;
            if (r >= Y0 - (7 - wv) && r <= Y0 + 70 - wv) CONVG(r);
        }
        __syncthreads();
    }
}

// ---------------------------------------------------------------------------
// Stats over x: float4 loads, per-wave LDS histograms, SSQ
// ---------------------------------------------------------------------------
__global__ __launch_bounds__(256) void k_stats_x(
    const float* __restrict__ x, unsigned* __restrict__ hist, float* __restrict__ sums)
{
    const int p = blockIdx.y;
    const f32x4* src = (const f32x4*)(x + (long long)p * HWSZ);
    __shared__ unsigned h[4][256];
    for (int i = threadIdx.x; i < 1024; i += 256) ((unsigned*)h)[i] = 0;
    __syncthreads();
    const int wid = threadIdx.x >> 6;

    float ss = 0.f;
    for (int i4 = blockIdx.x * 256 + threadIdx.x; i4 < HWSZ / 4; i4 += gridDim.x * 256) {
        const f32x4 v4 = src[i4];
#pragma unroll
        for (int e = 0; e < 4; ++e) {
            const float v = v4[e];
            ss += v * v;
            if (v >= -1.f && v <= 1.f) {
                int idx = (int)floorf((v + 1.f) * 128.f);
                idx = min(max(idx, 0), 255);
                atomicAdd(&h[wid][idx], 1u);
            }
        }
    }
    __syncthreads();
    const unsigned t = h[0][threadIdx.x] + h[1][threadIdx.x] +
                       h[2][threadIdx.x] + h[3][threadIdx.x];
    if (t) atomicAdd(&hist[p * 256 + threadIdx.x], t);

    float bs = blockSum(ss);
    if (threadIdx.x == 0) atomicAdd(&sums[0], bs);
}

// ---------------------------------------------------------------------------
// Stats over deltas, all 3 planes in one dispatch (z = channel).
// ---------------------------------------------------------------------------
__global__ __launch_bounds__(256) void k_stats_delta(
    const float* __restrict__ planes,
    unsigned* __restrict__ hist, float* __restrict__ sums)
{
    const int b = blockIdx.y, cz = blockIdx.z;
    const float* P = planes + ((long long)cz * BATCH + b) * HWSZ;
    const int row = b * 3 + cz;
    __shared__ unsigned h[4][256];
    for (int i = threadIdx.x; i < 1024; i += 256) ((unsigned*)h)[i] = 0;
    __syncthreads();
    const int wid = threadIdx.x >> 6;

    float ss = 0.f;
    for (int i4 = blockIdx.x * 256 + threadIdx.x; i4 < HWSZ / 4; i4 += gridDim.x * 256) {
        const int i0 = i4 * 4;
        const int y = i0 >> 9, x0 = i0 & (WW - 1);
        const f32x4 cur = ((const f32x4*)P)[i4];
        f32x4 up = { 0.f, 0.f, 0.f, 0.f };
        if (y) up = ((const f32x4*)P)[i4 - (WW / 4)];
        const float left = x0 ? P[i0 - 1] : 0.f;
        const float upl = (x0 && y) ? P[i0 - WW - 1] : 0.f;
#pragma unroll
        for (int e = 0; e < 4; ++e) {
            const float v = cur[e];
            const float n = up[e];
            const float wv = e ? cur[e - 1] : left;
            const float nw = e ? up[e - 1] : upl;
            float pr = n + wv - nw;
            pr = fminf(fmaxf(pr, fminf(n, wv)), fmaxf(n, wv));
            const float d = v - pr;
            ss += d * d;
            if (d >= -1.f && d <= 1.f) {
                int idx = (int)floorf((d + 1.f) * 128.f);
                idx = min(max(idx, 0), 255);
                atomicAdd(&h[wid][idx], 1u);
            }
        }
    }
    __syncthreads();
    const unsigned t = h[0][threadIdx.x] + h[1][threadIdx.x] +
                       h[2][threadIdx.x] + h[3][threadIdx.x];
    if (t) atomicAdd(&hist[row * 256 + threadIdx.x], t);

    float bs = blockSum(ss);
    if (threadIdx.x == 0) atomicAdd(&sums[1], bs);
}

// ---------------------------------------------------------------------------
// Finalize: entropies + the 4 output scalars
// ---------------------------------------------------------------------------
__global__ __launch_bounds__(256) void k_finalize(
    const unsigned* __restrict__ hist0, const unsigned* __restrict__ hist1,
    const float* __restrict__ sums, float* __restrict__ out)
{
    float e0 = 0.f, e1 = 0.f;
    for (int i = threadIdx.x; i < 48 * 256; i += 256) {
        float p0 = (float)hist0[i] * (1.0f / HWSZ);
        if (p0 > 0.f) e0 -= p0 * log2f(p0);
        float p1 = (float)hist1[i] * (1.0f / HWSZ);
        if (p1 > 0.f) e1 -= p1 * log2f(p1);
    }
    float t0 = blockSum(e0);
    float t1 = blockSum(e1);
    if (threadIdx.x == 0) {
        const float N = (float)BATCH * 3.f * (float)HWSZ;
        out[0] = 128.f * sqrtf(sums[1] / N);   // loss1 (deltas)
        out[1] = 128.f * sqrtf(sums[0] / N);   // loss0 (x)
        out[2] = t0 * (1.f / (8.f * 48.f));    // invcr0
        out[3] = t1 * (1.f / (8.f * 48.f));    // invcr1
    }
}

// ---------------------------------------------------------------------------
extern "C" void kernel_launch(void* const* d_in, const int* in_sizes, int n_in,
                              void* d_out, int out_size, void* d_ws, size_t ws_size,
                              hipStream_t stream) {
    const float* x = (const float*)d_in[0];
    const float* w[8];
    const float* bs[8];
    for (int i = 0; i < 8; ++i) {
        w[i]  = (const float*)d_in[1 + 2 * i];
        bs[i] = (const float*)d_in[2 + 2 * i];
    }

    // Workspace: planes (50.33 MB) + hists + sums only — no activation buffer.
    char* ws = (char*)d_ws;
    size_t o = 0;
    float* rpl = (float*)(ws + o); o += (size_t)BATCH * HWSZ * 4;
    float* gpl = (float*)(ws + o); o += (size_t)BATCH * HWSZ * 4;
    float* bpl = (float*)(ws + o); o += (size_t)BATCH * HWSZ * 4;
    unsigned* hist0 = (unsigned*)(ws + o); o += 48 * 256 * 4;
    unsigned* hist1 = (unsigned*)(ws + o); o += 48 * 256 * 4;
    float* sums = (float*)(ws + o); o += 256;

    hipMemsetAsync(hist0, 0, 48 * 256 * 4 * 2 + 256, stream);

    const dim3 gq(WW / 64, HH / 64, BATCH);

    auto predictor = [&](const float* pa, long long sa, const float* pb, long long sb,
                         const float* xs, float* outp) {
        k_pred8<<<gq, 512, 0, stream>>>(
            pa, sa, pb, sb, xs, 3LL * HWSZ, outp,
            w[0], bs[0], w[1], bs[1], w[2], bs[2], w[3], bs[3],
            w[4], bs[4], w[5], bs[5], w[6], bs[6], w[7], bs[7]);
    };

    // r = x_r - pred(g, b);  g = x_g - pred(r, b);  b = x_b - pred(r, g)
    predictor(x + 1LL * HWSZ, 3LL * HWSZ, x + 2LL * HWSZ, 3LL * HWSZ,
              x + 0LL * HWSZ, rpl);
    predictor(rpl, (long long)HWSZ, x + 2LL * HWSZ, 3LL * HWSZ,
              x + 1LL * HWSZ, gpl);
    predictor(rpl, (long long)HWSZ, gpl, (long long)HWSZ,
              x + 2LL * HWSZ, bpl);

    const dim3 sgrid(64, 48);
    k_stats_x<<<sgrid, 256, 0, stream>>>(x, hist0, sums);
    const dim3 dgrid(64, BATCH, 3);
    k_stats_delta<<<dgrid, 256, 0, stream>>>(rpl, hist1, sums);

    k_finalize<<<1, 256, 0, stream>>>(hist0, hist1, sums, (float*)d_out);
}

// Round 22
// 1170.728 us; speedup vs baseline: 2.0850x; 1.1169x over previous
//
#include <hip/hip_runtime.h>
#include <hip/hip_bf16.h>

typedef __hip_bfloat16 hbf16;
typedef __attribute__((ext_vector_type(8))) short bfrag8;
typedef __attribute__((ext_vector_type(4))) short short4v;
typedef __attribute__((ext_vector_type(4))) float f32x4;

#define BATCH 16
#define HH 512
#define WW 512
#define HWSZ (HH * WW)
#define STRIPH 128
#define NSTEPS (STRIPH + 24)

__device__ __forceinline__ short f2bf(float f) {
    hbf16 h = __float2bfloat16(f);
    return *(short*)&h;
}

__device__ __forceinline__ float blockSum(float v) {
#pragma unroll
    for (int o = 32; o > 0; o >>= 1) v += __shfl_down(v, o, 64);
    __shared__ float sh[4];
    const int lane = threadIdx.x & 63, wid = threadIdx.x >> 6;
    if (lane == 0) sh[wid] = v;
    __syncthreads();
    float r = 0.f;
    if (threadIdx.x == 0) r = sh[0] + sh[1] + sh[2] + sh[3];
    __syncthreads();
    return r;
}

// ---------------------------------------------------------------------------
// Full 8-layer predictor, software-pipelined (R21-verified structure).
// 512 thr = 8 waves; wave w owns layer w; one barrier per step; skew 2.
// NEW vs R21: (a) half-split window layout [slot][2 hf][PW][8ch] -> 16B pixel
// stride -> 2-way LDS bank conflicts (free) instead of 4-way; (b) STRIPH=128
// -> 512 blocks = exactly 2 resident/CU, one residency wave, 152 steps.
// Windows: fin 4x80x2ch; window l (l=0..6) 4 slots x 2 hf x (78-2l) x 8ch,
// packed in aW at short-offset 64*l*(79-l). LDS 65.8 KB -> 2 blocks/CU.
// ---------------------------------------------------------------------------
__global__ __launch_bounds__(512) void k_pred8(
    const float* __restrict__ p0, long long s0,
    const float* __restrict__ p1, long long s1,
    const float* __restrict__ xsrc, long long xstride,
    float* __restrict__ outp,
    const float* __restrict__ w0, const float* __restrict__ b0,
    const float* __restrict__ w1, const float* __restrict__ b1,
    const float* __restrict__ w2, const float* __restrict__ b2,
    const float* __restrict__ w3, const float* __restrict__ b3,
    const float* __restrict__ w4, const float* __restrict__ b4,
    const float* __restrict__ w5, const float* __restrict__ b5,
    const float* __restrict__ w6, const float* __restrict__ b6,
    const float* __restrict__ w7, const float* __restrict__ b7)
{
    __shared__ short finW[4 * 80 * 2];     //  1,280 B
    __shared__ short aW[4 * 504 * 16];     // 64,512 B (a0..a6, half-split)

    const int tid = threadIdx.x, lane = tid & 63, wv = tid >> 6;
    const int tx0 = blockIdx.x * 64, Y0 = blockIdx.y * STRIPH;
    const long long b = blockIdx.z;
    const float* pa = p0 + b * s0;
    const float* pb = p1 + b * s1;
    const float* xb = xsrc + b * xstride;
    float* ob = outp + b * (long long)HWSZ;

    const int arow = lane & 15, grp = lane >> 4, lx = lane & 15;
    const int hf = grp & 1;                // read half (cib>>3)
    const int cib = hf * 8, kofb = grp >> 1;
    const int c0 = grp * 4;
    const int hfw = grp >> 1;              // write half (c0>=8)
    const int cw = (grp & 1) * 4;          // c0 & 7

    // per-wave window geometry (layer wv): in = window wv-1, out = window wv
    const short* inw = aW + 64 * (wv - 1) * (80 - wv);   // valid for wv>=1
    short* outw = aW + 64 * wv * (79 - wv);              // valid for wv<=6
    const int IW = 80 - 2 * wv, OW = 78 - 2 * wv;

    // per-wave weight fragments + tap offsets
    bfrag8 myf[5];
    int dys[5], dxs[5];
    float mb0 = 0.f, mb1 = 0.f, mb2 = 0.f, mb3 = 0.f;
#pragma unroll
    for (int s = 0; s < 5; ++s) {
        const int koff = 2 * s + kofb;
        const int kc = (koff < 9) ? koff : 8;
        dys[s] = kc / 3; dxs[s] = kc - dys[s] * 3;
#pragma unroll
        for (int j = 0; j < 8; ++j) myf[s][j] = 0;
    }
    if (wv == 0) {
#pragma unroll
        for (int j = 0; j < 8; ++j) {
            const int k = grp * 8 + j;
            myf[0][j] = (k < 18) ? f2bf(w0[arow * 18 + (k & 1) * 9 + (k >> 1)])
                                 : (short)0;
        }
        mb0 = b0[c0]; mb1 = b0[c0 + 1]; mb2 = b0[c0 + 2]; mb3 = b0[c0 + 3];
    } else {
        const float* wp = (wv == 1) ? w1 : (wv == 2) ? w2 : (wv == 3) ? w3 :
                          (wv == 4) ? w4 : (wv == 5) ? w5 : (wv == 6) ? w6 : w7;
        const float* bp = (wv == 1) ? b1 : (wv == 2) ? b2 : (wv == 3) ? b3 :
                          (wv == 4) ? b4 : (wv == 5) ? b5 : (wv == 6) ? b6 : b7;
        const bool rmask = (wv < 7) || (arow < 3);
#pragma unroll
        for (int s = 0; s < 5; ++s) {
            const int koff = 2 * s + kofb;
#pragma unroll
            for (int j = 0; j < 8; ++j)
                myf[s][j] = (rmask && koff < 9)
                              ? f2bf(wp[(arow * 16 + cib + j) * 9 + koff])
                              : (short)0;
        }
        if (wv == 7) {
            mb0 = (grp == 0) ? bp[0] : 0.f;
            mb1 = (grp == 0) ? bp[1] : 0.f;
            mb2 = (grp == 0) ? bp[2] : 0.f;
        } else {
            mb0 = bp[c0]; mb1 = bp[c0 + 1]; mb2 = bp[c0 + 2]; mb3 = bp[c0 + 3];
        }
    }

    // generic conv row (layers 1..6): inw/IW -> outw/OW, global row gr
    auto CONVG = [&](int gr) {
        const bool rok = ((unsigned)gr < (unsigned)HH);
        const int halo = (OW - 64) >> 1;
        const int rm1 = (((gr - 1) & 3) * 2 + hf) * IW;
        const int r00 = (((gr    ) & 3) * 2 + hf) * IW;
        const int rp1 = (((gr + 1) & 3) * 2 + hf) * IW;
        const int wbase = ((gr & 3) * 2 + hfw) * OW;
#pragma unroll
        for (int c = 0; c < 5; ++c) {
            const int xr = c * 16 + lx;
            const int xc = (xr < OW) ? xr : (OW - 1);
            f32x4 a = { mb0, mb1, mb2, mb3 };
#pragma unroll
            for (int s = 0; s < 5; ++s) {
                const int rof = (dys[s] == 0) ? rm1 : ((dys[s] == 2) ? rp1 : r00);
                const bfrag8 q = *(const bfrag8*)&inw[(rof + xc + dxs[s]) * 8];
                a = __builtin_amdgcn_mfma_f32_16x16x32_bf16(myf[s], q, a, 0, 0, 0);
            }
            if (xr < OW) {
                const int gx = tx0 - halo + xr;
                const bool ok = rok && ((unsigned)gx < (unsigned)WW);
                short4v st;
#pragma unroll
                for (int i = 0; i < 4; ++i) {
                    float r = a[i]; r = (r >= 0.f) ? r : 0.01f * r;
                    st[i] = ok ? f2bf(r) : (short)0;
                }
                *(short4v*)&outw[(wbase + xr) * 8 + cw] = st;
            }
        }
    };

    // L0 row (wave 0): fin gather (K=18) -> window 0 (width 78, halo 7)
    auto L0ROW = [&](int gr) {
        const bool rok = ((unsigned)gr < (unsigned)HH);
        const int rm1 = ((gr - 1) & 3) * 80, r00 = (gr & 3) * 80,
                  rp1 = ((gr + 1) & 3) * 80;
        const int wbase = ((gr & 3) * 2 + hfw) * 78;
        short* a0w = aW;
#pragma unroll
        for (int c = 0; c < 5; ++c) {
            const int xr = c * 16 + lx;
            const int xc = (xr < 78) ? xr : 77;
            bfrag8 bf;
#pragma unroll
            for (int j = 0; j < 8; ++j) {
                const int k = grp * 8 + j;
                short v = 0;
                if (k < 18) {
                    const int tap = k >> 1, dy = tap / 3, dx = tap - dy * 3;
                    const int ro = (dy == 0) ? rm1 : ((dy == 2) ? rp1 : r00);
                    v = finW[(ro + xc + dx) * 2 + (k & 1)];
                }
                bf[j] = v;
            }
            f32x4 a = { mb0, mb1, mb2, mb3 };
            a = __builtin_amdgcn_mfma_f32_16x16x32_bf16(myf[0], bf, a, 0, 0, 0);
            if (xr < 78) {
                const int gx = tx0 - 7 + xr;
                const bool ok = rok && ((unsigned)gx < (unsigned)WW);
                short4v st;
#pragma unroll
                for (int i = 0; i < 4; ++i) {
                    float r = a[i]; r = (r >= 0.f) ? r : 0.01f * r;
                    st[i] = ok ? f2bf(r) : (short)0;
                }
                *(short4v*)&a0w[(wbase + xr) * 8 + cw] = st;
            }
        }
    };

    // L7 row (wave 7): window 6 (width 66) -> clip/median3/(x - med) -> global
    auto OUT7 = [&](int gr) {
        const int rm1 = (((gr - 1) & 3) * 2 + hf) * 66;
        const int r00 = (((gr    ) & 3) * 2 + hf) * 66;
        const int rp1 = (((gr + 1) & 3) * 2 + hf) * 66;
#pragma unroll
        for (int c = 0; c < 4; ++c) {
            const int o = c * 16 + lx;
            f32x4 a = { mb0, mb1, mb2, 0.f };
#pragma unroll
            for (int s = 0; s < 5; ++s) {
                const int rof = (dys[s] == 0) ? rm1 : ((dys[s] == 2) ? rp1 : r00);
                const bfrag8 q = *(const bfrag8*)&inw[(rof + o + dxs[s]) * 8];
                a = __builtin_amdgcn_mfma_f32_16x16x32_bf16(myf[s], q, a, 0, 0, 0);
            }
            if (grp == 0) {
                float y0 = fminf(fmaxf(a[0], -1.f), 1.f);
                float y1 = fminf(fmaxf(a[1], -1.f), 1.f);
                float y2 = fminf(fmaxf(a[2], -1.f), 1.f);
                float med = fmaxf(fminf(y0, fmaxf(y1, y2)), fminf(y1, y2));
                const long long pix = (long long)gr * WW + tx0 + o;
                ob[pix] = xb[pix] - med;
            }
        }
    };

    // main pipeline: NSTEPS steps, ONE barrier each
    for (int S = 0; S < NSTEPS; ++S) {
        if (wv == 7) {
            const int R = Y0 - 8 + S;
            const bool doStage = (S < STRIPH + 16);
            float v0 = 0.f, v1 = 0.f, v2 = 0.f;
            if (doStage) {
                const int i0 = lane, i1 = lane + 64, i2 = lane + 128;
                {
                    const int xx = i0 >> 1, ci = i0 & 1, gx = tx0 - 8 + xx;
                    if ((unsigned)R < (unsigned)HH && (unsigned)gx < (unsigned)WW)
                        v0 = (ci ? pb : pa)[R * WW + gx];
                }
                {
                    const int xx = i1 >> 1, ci = i1 & 1, gx = tx0 - 8 + xx;
                    if ((unsigned)R < (unsigned)HH && (unsigned)gx < (unsigned)WW)
                        v1 = (ci ? pb : pa)[R * WW + gx];
                }
                if (i2 < 160) {
                    const int xx = i2 >> 1, ci = i2 & 1, gx = tx0 - 8 + xx;
                    if ((unsigned)R < (unsigned)HH && (unsigned)gx < (unsigned)WW)
                        v2 = (ci ? pb : pa)[R * WW + gx];
                }
            }
            const int r7 = Y0 - 24 + S;
            if (r7 >= Y0 && r7 <= Y0 + STRIPH - 1) OUT7(r7);
            if (doStage) {
                const int base = (R & 3) * 80;
                const int i0 = lane, i1 = lane + 64, i2 = lane + 128;
                finW[(base + (i0 >> 1)) * 2 + (i0 & 1)] = f2bf(v0);
                finW[(base + (i1 >> 1)) * 2 + (i1 & 1)] = f2bf(v1);
                if (i2 < 160)
                    finW[(base + (i2 >> 1)) * 2 + (i2 & 1)] = f2bf(v2);
            }
        } else if (wv == 0) {
            const int r0 = Y0 - 10 + S;
            if (r0 >= Y0 - 7 && r0 <= Y0 + STRIPH + 6) L0ROW(r0);
        } else {
            const int r = Y0 - 10 + S - 2 * wv;
            if (r >= Y0 - (7 - wv) && r <= Y0 + STRIPH + 6 - wv) CONVG(r);
        }
        __syncthreads();
    }
}

// ---------------------------------------------------------------------------
// Stats over x: float4 loads, per-wave LDS histograms, SSQ
// ---------------------------------------------------------------------------
__global__ __launch_bounds__(256) void k_stats_x(
    const float* __restrict__ x, unsigned* __restrict__ hist, float* __restrict__ sums)
{
    const int p = blockIdx.y;
    const f32x4* src = (const f32x4*)(x + (long long)p * HWSZ);
    __shared__ unsigned h[4][256];
    for (int i = threadIdx.x; i < 1024; i += 256) ((unsigned*)h)[i] = 0;
    __syncthreads();
    const int wid = threadIdx.x >> 6;

    float ss = 0.f;
    for (int i4 = blockIdx.x * 256 + threadIdx.x; i4 < HWSZ / 4; i4 += gridDim.x * 256) {
        const f32x4 v4 = src[i4];
#pragma unroll
        for (int e = 0; e < 4; ++e) {
            const float v = v4[e];
            ss += v * v;
            if (v >= -1.f && v <= 1.f) {
                int idx = (int)floorf((v + 1.f) * 128.f);
                idx = min(max(idx, 0), 255);
                atomicAdd(&h[wid][idx], 1u);
            }
        }
    }
    __syncthreads();
    const unsigned t = h[0][threadIdx.x] + h[1][threadIdx.x] +
                       h[2][threadIdx.x] + h[3][threadIdx.x];
    if (t) atomicAdd(&hist[p * 256 + threadIdx.x], t);

    float bs = blockSum(ss);
    if (threadIdx.x == 0) atomicAdd(&sums[0], bs);
}

// ---------------------------------------------------------------------------
// Stats over deltas, all 3 planes in one dispatch (z = channel).
// ---------------------------------------------------------------------------
__global__ __launch_bounds__(256) void k_stats_delta(
    const float* __restrict__ planes,
    unsigned* __restrict__ hist, float* __restrict__ sums)
{
    const int b = blockIdx.y, cz = blockIdx.z;
    const float* P = planes + ((long long)cz * BATCH + b) * HWSZ;
    const int row = b * 3 + cz;
    __shared__ unsigned h[4][256];
    for (int i = threadIdx.x; i < 1024; i += 256) ((unsigned*)h)[i] = 0;
    __syncthreads();
    const int wid = threadIdx.x >> 6;

    float ss = 0.f;
    for (int i4 = blockIdx.x * 256 + threadIdx.x; i4 < HWSZ / 4; i4 += gridDim.x * 256) {
        const int i0 = i4 * 4;
        const int y = i0 >> 9, x0 = i0 & (WW - 1);
        const f32x4 cur = ((const f32x4*)P)[i4];
        f32x4 up = { 0.f, 0.f, 0.f, 0.f };
        if (y) up = ((const f32x4*)P)[i4 - (WW / 4)];
        const float left = x0 ? P[i0 - 1] : 0.f;
        const float upl = (x0 && y) ? P[i0 - WW - 1] : 0.f;
#pragma unroll
        for (int e = 0; e < 4; ++e) {
            const float v = cur[e];
            const float n = up[e];
            const float wv = e ? cur[e - 1] : left;
            const float nw = e ? up[e - 1] : upl;
            float pr = n + wv - nw;
            pr = fminf(fmaxf(pr, fminf(n, wv)), fmaxf(n, wv));
            const float d = v - pr;
            ss += d * d;
            if (d >= -1.f && d <= 1.f) {
                int idx = (int)floorf((d + 1.f) * 128.f);
                idx = min(max(idx, 0), 255);
                atomicAdd(&h[wid][idx], 1u);
            }
        }
    }
    __syncthreads();
    const unsigned t = h[0][threadIdx.x] + h[1][threadIdx.x] +
                       h[2][threadIdx.x] + h[3][threadIdx.x];
    if (t) atomicAdd(&hist[row * 256 + threadIdx.x], t);

    float bs = blockSum(ss);
    if (threadIdx.x == 0) atomicAdd(&sums[1], bs);
}

// ---------------------------------------------------------------------------
// Finalize: entropies + the 4 output scalars
// ---------------------------------------------------------------------------
__global__ __launch_bounds__(256) void k_finalize(
    const unsigned* __restrict__ hist0, const unsigned* __restrict__ hist1,
    const float* __restrict__ sums, float* __restrict__ out)
{
    float e0 = 0.f, e1 = 0.f;
    for (int i = threadIdx.x; i < 48 * 256; i += 256) {
        float p0 = (float)hist0[i] * (1.0f / HWSZ);
        if (p0 > 0.f) e0 -= p0 * log2f(p0);
        float p1 = (float)hist1[i] * (1.0f / HWSZ);
        if (p1 > 0.f) e1 -= p1 * log2f(p1);
    }
    float t0 = blockSum(e0);
    float t1 = blockSum(e1);
    if (threadIdx.x == 0) {
        const float N = (float)BATCH * 3.f * (float)HWSZ;
        out[0] = 128.f * sqrtf(sums[1] / N);   // loss1 (deltas)
        out[1] = 128.f * sqrtf(sums[0] / N);   // loss0 (x)
        out[2] = t0 * (1.f / (8.f * 48.f));    // invcr0
        out[3] = t1 * (1.f / (8.f * 48.f));    // invcr1
    }
}

// ---------------------------------------------------------------------------
extern "C" void kernel_launch(void* const* d_in, const int* in_sizes, int n_in,
                              void* d_out, int out_size, void* d_ws, size_t ws_size,
                              hipStream_t stream) {
    const float* x = (const float*)d_in[0];
    const float* w[8];
    const float* bs[8];
    for (int i = 0; i < 8; ++i) {
        w[i]  = (const float*)d_in[1 + 2 * i];
        bs[i] = (const float*)d_in[2 + 2 * i];
    }

    // Workspace: planes (50.33 MB) + hists + sums only — no activation buffer.
    char* ws = (char*)d_ws;
    size_t o = 0;
    float* rpl = (float*)(ws + o); o += (size_t)BATCH * HWSZ * 4;
    float* gpl = (float*)(ws + o); o += (size_t)BATCH * HWSZ * 4;
    float* bpl = (float*)(ws + o); o += (size_t)BATCH * HWSZ * 4;
    unsigned* hist0 = (unsigned*)(ws + o); o += 48 * 256 * 4;
    unsigned* hist1 = (unsigned*)(ws + o); o += 48 * 256 * 4;
    float* sums = (float*)(ws + o); o += 256;

    hipMemsetAsync(hist0, 0, 48 * 256 * 4 * 2 + 256, stream);

    const dim3 gq(WW / 64, HH / STRIPH, BATCH);

    auto predictor = [&](const float* pa, long long sa, const float* pb, long long sb,
                         const float* xs, float* outp) {
        k_pred8<<<gq, 512, 0, stream>>>(
            pa, sa, pb, sb, xs, 3LL * HWSZ, outp,
            w[0], bs[0], w[1], bs[1], w[2], bs[2], w[3], bs[3],
            w[4], bs[4], w[5], bs[5], w[6], bs[6], w[7], bs[7]);
    };

    // r = x_r - pred(g, b);  g = x_g - pred(r, b);  b = x_b - pred(r, g)
    predictor(x + 1LL * HWSZ, 3LL * HWSZ, x + 2LL * HWSZ, 3LL * HWSZ,
              x + 0LL * HWSZ, rpl);
    predictor(rpl, (long long)HWSZ, x + 2LL * HWSZ, 3LL * HWSZ,
              x + 1LL * HWSZ, gpl);
    predictor(rpl, (long long)HWSZ, gpl, (long long)HWSZ,
              x + 2LL * HWSZ, bpl);

    const dim3 sgrid(64, 48);
    k_stats_x<<<sgrid, 256, 0, stream>>>(x, hist0, sums);
    const dim3 dgrid(64, BATCH, 3);
    k_stats_delta<<<dgrid, 256, 0, stream>>>(rpl, hist1, sums);

    k_finalize<<<1, 256, 0, stream>>>(hist0, hist1, sums, (float*)d_out);
}